// Round 7
// baseline (157.720 us; speedup 1.0000x reference)
//
#include <hip/hip_runtime.h>
#include <stdint.h>

#define N_ANCH 102400
#define FMP 320
#define K_TOP 1000
#define NMS_T 0.6f
#define SC_CLAMP 6.907755278982137f
#define IMGF 1280.0f
#define NBINS 16384   // scores in (0,1) => float bits>>16 < 0x4000

// ---- workspace layout (bytes) ----
#define OFF_SCORES   0u          // f32[102400]
#define OFF_LABELS   409600u     // u32[102400]
#define OFF_HIST     819200u     // u32[16384]
#define OFF_BOXES    917760u     // f32[4000]
#define OFF_LAB1K    933760u     // u32[1000]
#define OFF_MASK     937760u     // u64[16000]
#define OFF_DIAG     1065760u    // u64[1024]

__device__ __forceinline__ float sigf(float x) {
    return 1.0f / (1.0f + expf(-x));
}

// ---------------- K1: scores+argmax; fused zeroing of hist/diag ----------------
__global__ __launch_bounds__(256) void k_scores(const float* __restrict__ hmp,
                                                const float* __restrict__ iou,
                                                float* __restrict__ scores,
                                                uint32_t* __restrict__ labels,
                                                uint32_t* __restrict__ hist,
                                                uint64_t* __restrict__ diag) {
    int blk = blockIdx.x;
    if (blk < 64) {
        hist[blk * 256 + threadIdx.x] = 0u;     // 64*256 = 16384 bins zeroed
    } else if (blk == 64) {
        // zero diag (k_mask only rewrites rows < 1000; k_scan reads all 1024;
        // harness re-poisons ws every iteration so this is mandatory)
#pragma unroll
        for (int k = 0; k < 4; ++k) diag[threadIdx.x * 4 + k] = 0ull;
    }
    int gid = blk * 256 + threadIdx.x;
    int a = gid >> 2;
    int q = gid & 3;
    float si = sigf(iou[a]);
    const float4* row4 = (const float4*)hmp + (size_t)a * 20 + q;
    float4 v[5];
#pragma unroll
    for (int j = 0; j < 5; ++j) v[j] = row4[j * 4];
    float best = -1.0f;
    int bc = 0;
#pragma unroll
    for (int j = 0; j < 5; ++j) {
        int cb = j * 16 + q * 4;
        float f;
        f = sqrtf(sigf(v[j].x) * si); if (f > best) { best = f; bc = cb; }
        f = sqrtf(sigf(v[j].y) * si); if (f > best) { best = f; bc = cb + 1; }
        f = sqrtf(sigf(v[j].z) * si); if (f > best) { best = f; bc = cb + 2; }
        f = sqrtf(sigf(v[j].w) * si); if (f > best) { best = f; bc = cb + 3; }
    }
#pragma unroll
    for (int off = 1; off <= 2; off <<= 1) {
        float of = __shfl_xor(best, off);
        int   oc = __shfl_xor(bc, off);
        if (of > best || (of == best && oc < bc)) { best = of; bc = oc; }
    }
    if (q == 0) {
        scores[a] = best;
        labels[a] = (uint32_t)bc;
    }
}

// ---------------- K2: parallel histogram build (32 blocks), atomic flush only ----------------
// Kernel boundary is the sync. LDS pre-aggregation keeps global atomics to non-zero bins.
__global__ __launch_bounds__(1024) void k_hist(const float* __restrict__ scores,
                                               uint32_t* __restrict__ hist) {
    __shared__ uint32_t lh[NBINS];
    const int tid = threadIdx.x;
    for (int i = tid; i < NBINS; i += 1024) lh[i] = 0u;
    __syncthreads();
    int base = blockIdx.x * 3200;
    for (int k = tid; k < 3200; k += 1024) {
        uint32_t bin = __float_as_uint(scores[base + k]) >> 16;
        atomicAdd(&lh[bin], 1u);
    }
    __syncthreads();
    for (int i = tid; i < NBINS; i += 1024) {
        uint32_t c = lh[i];
        if (c) atomicAdd(&hist[i], c);
    }
}

// ---------------- K3: 64 blocks; redundant cut + redundant FULL collect in LDS,
// then rank+decode for the deterministic partition (anchor_idx & 63 == blockIdx).
// Rank-by-comparison is append-order-independent, so per-block nondeterministic
// LDS append order is harmless; partition-by-index gives exactly-once outputs.
// Replaces the old k_cutcollect + k_rank pair (one fewer dispatch + gap, no keys
// global round-trip). Scores are L2-resident (400 KB) after k_hist's sweep.
__global__ __launch_bounds__(1024) void k_select(const float* __restrict__ scores,
                                                 const uint32_t* __restrict__ hist,
                                                 const uint32_t* __restrict__ labels,
                                                 const float* __restrict__ reg,
                                                 float* __restrict__ out,
                                                 float* __restrict__ boxes,
                                                 uint32_t* __restrict__ lab1k) {
    __shared__ uint32_t lh[NBINS];        // 64 KB fine histogram
    __shared__ uint32_t coarse[1024];     // suffix sums at 16-bin granularity
    __shared__ uint64_t skey[4096];       // ALL candidates (redundant per block)
    __shared__ uint32_t s_cut, cnt;

    const int tid = threadIdx.x;
    const int blk = blockIdx.x;

    // vectorized 64 KB hist load
    const uint4* h4 = (const uint4*)hist;
    for (int i = tid; i < NBINS / 4; i += 1024) {
        uint4 v = h4[i];
        lh[i * 4 + 0] = v.x; lh[i * 4 + 1] = v.y;
        lh[i * 4 + 2] = v.z; lh[i * 4 + 3] = v.w;
    }
    if (tid == 0) { s_cut = 0u; cnt = 0u; }
    __syncthreads();

    // --- coarse sums (16 bins/thread) + suffix scan; lh keeps original counts ---
    {
        uint32_t s = 0;
#pragma unroll
        for (int b = 0; b < 16; ++b) s += lh[tid * 16 + b];
        coarse[tid] = s;
    }
    __syncthreads();
    for (int off = 1; off < 1024; off <<= 1) {
        uint32_t v = coarse[tid] + ((tid + off < 1024) ? coarse[tid + off] : 0u);
        __syncthreads();
        coarse[tid] = v;
        __syncthreads();
    }
    {
        uint32_t inc   = coarse[tid];
        uint32_t above = (tid < 1023) ? coarse[tid + 1] : 0u;
        if (above < K_TOP && inc >= K_TOP) {
            uint32_t c2 = above;
            for (int b = 15; b >= 0; --b) {
                c2 += lh[tid * 16 + b];
                if (c2 >= K_TOP) { s_cut = (uint32_t)(tid * 16 + b); break; }
            }
        }
    }
    __syncthreads();

    // --- redundant full collect: sweep ALL scores, append every candidate ---
    const uint32_t cut = s_cut;
    const float4* s4 = (const float4*)scores;
    for (int k = tid; k < N_ANCH / 4; k += 1024) {
        float4 v = s4[k];
        uint32_t bb[4] = { __float_as_uint(v.x), __float_as_uint(v.y),
                           __float_as_uint(v.z), __float_as_uint(v.w) };
#pragma unroll
        for (int c = 0; c < 4; ++c) {
            if ((bb[c] >> 16) >= cut) {
                uint32_t p = atomicAdd(&cnt, 1u);
                if (p < 4096u)
                    skey[p] = ((uint64_t)bb[c] << 32) |
                              (uint64_t)(0xFFFFFFFFu - (uint32_t)(k * 4 + c));
            }
        }
    }
    __syncthreads();

    // --- rank+decode: this block owns candidates with (idx & 63) == blk ---
    uint32_t M = cnt;
    if (M > 4096u) M = 4096u;
    const int lane = tid & 63;
    const int wv = tid >> 6;            // 16 waves
    for (uint32_t c = (uint32_t)wv; c < M; c += 16u) {
        uint64_t key = skey[c];
        uint32_t idx = 0xFFFFFFFFu - (uint32_t)(key & 0xFFFFFFFFull);
        if ((int)(idx & 63u) != blk) continue;   // wave-uniform: key is uniform per wave
        uint32_t rank = 0;
        for (uint32_t j = (uint32_t)lane; j < M; j += 64u)
            rank += (skey[j] > key) ? 1u : 0u;
#pragma unroll
        for (int off = 32; off; off >>= 1) rank += __shfl_xor(rank, off);
        if (lane != 0 || rank >= K_TOP) continue;
        int t = (int)rank;
        float score = __uint_as_float((uint32_t)(key >> 32));
        uint32_t lab = labels[idx];
        out[t]         = score;
        out[K_TOP + t] = (float)lab;
        lab1k[t]       = lab;
        float ax = (float)(idx % FMP);
        float ay = (float)(idx / FMP);
        float4 rr = ((const float4*)reg)[idx];
        float e0 = expf(fminf(rr.x, SC_CLAMP));
        float e1 = expf(fminf(rr.y, SC_CLAMP));
        float e2 = expf(fminf(rr.z, SC_CLAMP));
        float e3 = expf(fminf(rr.w, SC_CLAMP));
        float x1 = fminf(fmaxf((ax - e0) * 4.0f / IMGF, 0.0f), 1.0f);
        float y1 = fminf(fmaxf((ay - e1) * 4.0f / IMGF, 0.0f), 1.0f);
        float x2 = fminf(fmaxf((ax + e2) * 4.0f / IMGF, 0.0f), 1.0f);
        float y2 = fminf(fmaxf((ay + e3) * 4.0f / IMGF, 0.0f), 1.0f);
        out[2 * K_TOP + t * 4 + 0] = x1;
        out[2 * K_TOP + t * 4 + 1] = y1;
        out[2 * K_TOP + t * 4 + 2] = x2;
        out[2 * K_TOP + t * 4 + 3] = y2;
        boxes[t * 4 + 0] = x1;
        boxes[t * 4 + 1] = y1;
        boxes[t * 4 + 2] = x2;
        boxes[t * 4 + 3] = y2;
    }
}

// ---------------- K4: suppress masks, one wave per row (63 x 1024) ----------------
__global__ __launch_bounds__(1024) void k_mask(const float* __restrict__ boxes,
                                               const uint32_t* __restrict__ lab1k,
                                               uint64_t* __restrict__ mask,
                                               uint64_t* __restrict__ diag) {
    int r = blockIdx.x * 16 + (threadIdx.x >> 6);
    int lane = threadIdx.x & 63;
    if (r >= K_TOP) return;
    float4 bi = ((const float4*)boxes)[r];
    uint32_t li = lab1k[r];
    float areai = (bi.z - bi.x) * (bi.w - bi.y);
    int iw = r >> 6;
    uint64_t dw = 0ull;
#pragma unroll
    for (int w = 0; w < 16; ++w) {
        int j = w * 64 + lane;
        bool sup = false;
        if (j < K_TOP && j > r) {
            float4 bj = ((const float4*)boxes)[j];
            float areaj = (bj.z - bj.x) * (bj.w - bj.y);
            float xx1 = fmaxf(bi.x, bj.x);
            float yy1 = fmaxf(bi.y, bj.y);
            float xx2 = fminf(bi.z, bj.z);
            float yy2 = fminf(bi.w, bj.w);
            float ww = fmaxf(1e-10f, xx2 - xx1);
            float hh = fmaxf(1e-10f, yy2 - yy1);
            float inter = ww * hh;
            float iouv = inter / (areai + areaj - inter + 1e-10f);
            sup = (iouv > NMS_T) && (li == lab1k[j]);
        }
        unsigned long long m = __ballot(sup);
        if (lane == 0) mask[(size_t)r * 16 + w] = (uint64_t)m;
        if (w == iw) dw = (uint64_t)m;
    }
    if (lane == 0) diag[r] = dw;
}

// ---------------- K5: greedy scan, single wave, full register budget ----------------
// launch_bounds(64,1): VGPR cap ~512 so bun[16] (32 VGPRs) can't spill
// (earlier fused versions compiled at VGPR=40 -> scratch -> 70-100us).
__global__ __launch_bounds__(64, 1) void k_scan(const uint64_t* __restrict__ mask,
                                                const uint64_t* __restrict__ diag,
                                                float* __restrict__ out) {
    int lane = threadIdx.x;
    int q = lane >> 4, wrd = lane & 15;
    uint64_t remv = 0ull;
    uint64_t dcur = diag[lane];
    for (int g = 0; g < 16; ++g) {
        uint64_t dnxt = (g < 15) ? diag[64 * (g + 1) + lane] : 0ull;
        uint64_t bun[16];
        if (g < 15) {
#pragma unroll
            for (int r4 = 0; r4 < 16; ++r4)
                bun[r4] = mask[(size_t)(64 * g + 4 * r4 + q) * 16 + wrd];
        }
        uint32_t dlo = 0, dhi = 0;
#pragma unroll
        for (int qq = 0; qq < 4; ++qq) {
            dlo |= __builtin_amdgcn_readlane((uint32_t)remv, qq * 16 + g);
            dhi |= __builtin_amdgcn_readlane((uint32_t)(remv >> 32), qq * 16 + g);
        }
        uint64_t D = ((uint64_t)dhi << 32) | dlo;
#pragma unroll
        for (int b = 0; b < 64; ++b) {
            uint32_t tlo = __builtin_amdgcn_readlane((uint32_t)dcur, b);
            uint32_t thi = __builtin_amdgcn_readlane((uint32_t)(dcur >> 32), b);
            uint64_t T = ((uint64_t)thi << 32) | tlo;
            uint64_t sel = ((D >> b) & 1ull) - 1ull;   // ~0 if row kept
            D |= T & sel;
        }
        uint64_t keepg = ~D;
        int j = g * 64 + lane;
        if (j < K_TOP) out[6 * K_TOP + j] = (float)((keepg >> lane) & 1ull);
        if (g < 15) {
#pragma unroll
            for (int r4 = 0; r4 < 16; ++r4) {
                uint32_t kb = (uint32_t)(keepg >> (4 * r4 + q)) & 1u;
                uint64_t mm = 0ull - (uint64_t)kb;
                remv |= bun[r4] & mm;
            }
        }
        dcur = dnxt;
    }
}

extern "C" void kernel_launch(void* const* d_in, const int* in_sizes, int n_in,
                              void* d_out, int out_size, void* d_ws, size_t ws_size,
                              hipStream_t stream) {
    const float* hmp = (const float*)d_in[0];
    const float* reg = (const float*)d_in[1];
    const float* iou = (const float*)d_in[2];
    float* out = (float*)d_out;
    char* ws = (char*)d_ws;

    float*    scores = (float*)(ws + OFF_SCORES);
    uint32_t* labels = (uint32_t*)(ws + OFF_LABELS);
    uint32_t* hist   = (uint32_t*)(ws + OFF_HIST);
    float*    boxes  = (float*)(ws + OFF_BOXES);
    uint32_t* lab1k  = (uint32_t*)(ws + OFF_LAB1K);
    uint64_t* mask   = (uint64_t*)(ws + OFF_MASK);
    uint64_t* diag   = (uint64_t*)(ws + OFF_DIAG);

    k_scores<<<dim3(N_ANCH * 4 / 256), dim3(256), 0, stream>>>(hmp, iou, scores, labels, hist, diag);
    k_hist<<<dim3(32), dim3(1024), 0, stream>>>(scores, hist);
    k_select<<<dim3(64), dim3(1024), 0, stream>>>(scores, hist, labels, reg, out, boxes, lab1k);
    k_mask<<<dim3(63), dim3(1024), 0, stream>>>(boxes, lab1k, mask, diag);
    k_scan<<<dim3(1), dim3(64), 0, stream>>>(mask, diag, out);
}

// Round 9
// 135.299 us; speedup vs baseline: 1.1657x; 1.1657x over previous
//
#include <hip/hip_runtime.h>
#include <stdint.h>

#define N_ANCH 102400
#define FMP 320
#define K_TOP 1000
#define NMS_T 0.6f
#define SC_CLAMP 6.907755278982137f
#define IMGF 1280.0f
#define NBINS 16384   // scores in (0,1) => float bits>>16 < 0x4000

// ---- workspace layout (bytes) ----
#define OFF_SCORES   0u          // f32[102400]
#define OFF_LABELS   409600u     // u32[102400]
#define OFF_HIST     819200u     // u32[16384]
#define OFF_META     884736u     // u32[64]: [2]=cand ctr
#define OFF_KEYS     884992u     // u64[4096]
#define OFF_BOXES    917760u     // f32[4000]
#define OFF_LAB1K    933760u     // u32[1000]
#define OFF_MASK     937760u     // u64[16000]
#define OFF_DIAG     1065760u    // u64[1024]

__device__ __forceinline__ float sigf(float x) {
    return 1.0f / (1.0f + expf(-x));
}

// ---------------- K1: scores+argmax; fused zeroing of hist/meta/diag ----------------
__global__ __launch_bounds__(256) void k_scores(const float* __restrict__ hmp,
                                                const float* __restrict__ iou,
                                                float* __restrict__ scores,
                                                uint32_t* __restrict__ labels,
                                                uint32_t* __restrict__ hist,
                                                uint32_t* __restrict__ meta,
                                                uint64_t* __restrict__ diag) {
    int blk = blockIdx.x;
    if (blk < 64) {
        hist[blk * 256 + threadIdx.x] = 0u;     // 64*256 = 16384 bins zeroed
    } else if (blk == 64) {
        if (threadIdx.x < 64) meta[threadIdx.x] = 0u;
        // zero diag (k_mask only rewrites rows < 1000; k_scan reads all 1024;
        // harness re-poisons ws every iteration so this is mandatory)
#pragma unroll
        for (int k = 0; k < 4; ++k) diag[threadIdx.x * 4 + k] = 0ull;
    }
    int gid = blk * 256 + threadIdx.x;
    int a = gid >> 2;
    int q = gid & 3;
    float si = sigf(iou[a]);
    const float4* row4 = (const float4*)hmp + (size_t)a * 20 + q;
    float4 v[5];
#pragma unroll
    for (int j = 0; j < 5; ++j) v[j] = row4[j * 4];
    float best = -1.0f;
    int bc = 0;
#pragma unroll
    for (int j = 0; j < 5; ++j) {
        int cb = j * 16 + q * 4;
        float f;
        f = sqrtf(sigf(v[j].x) * si); if (f > best) { best = f; bc = cb; }
        f = sqrtf(sigf(v[j].y) * si); if (f > best) { best = f; bc = cb + 1; }
        f = sqrtf(sigf(v[j].z) * si); if (f > best) { best = f; bc = cb + 2; }
        f = sqrtf(sigf(v[j].w) * si); if (f > best) { best = f; bc = cb + 3; }
    }
#pragma unroll
    for (int off = 1; off <= 2; off <<= 1) {
        float of = __shfl_xor(best, off);
        int   oc = __shfl_xor(bc, off);
        if (of > best || (of == best && oc < bc)) { best = of; bc = oc; }
    }
    if (q == 0) {
        scores[a] = best;
        labels[a] = (uint32_t)bc;
    }
}

// ---------------- K2: parallel histogram build (32 blocks), atomic flush only ----------------
// Kernel boundary is the sync. LDS pre-aggregation keeps global atomics to non-zero
// bins (~hundreds/block to ~8 hot cache lines — cheap; direct per-score global atomics
// would serialize ~100K ops on those lines).
__global__ __launch_bounds__(1024) void k_hist(const float* __restrict__ scores,
                                               uint32_t* __restrict__ hist) {
    __shared__ uint32_t lh[NBINS];
    const int tid = threadIdx.x;
    for (int i = tid; i < NBINS; i += 1024) lh[i] = 0u;
    __syncthreads();
    // 3200 scores/block = 800 float4
    const float4* s4 = (const float4*)(scores + blockIdx.x * 3200);
    for (int k = tid; k < 800; k += 1024) {
        float4 v = s4[k];
        atomicAdd(&lh[__float_as_uint(v.x) >> 16], 1u);
        atomicAdd(&lh[__float_as_uint(v.y) >> 16], 1u);
        atomicAdd(&lh[__float_as_uint(v.z) >> 16], 1u);
        atomicAdd(&lh[__float_as_uint(v.w) >> 16], 1u);
    }
    __syncthreads();
    for (int i = tid; i < NBINS; i += 1024) {
        uint32_t c = lh[i];
        if (c) atomicAdd(&hist[i], c);
    }
}

// ---------------- K3: 64 blocks; each redundantly computes cut, then collects its slice ----------------
// cut is a deterministic function of the complete hist, so all blocks agree without
// any cross-block exchange. Append is block-aggregated (one global atomic per block).
__global__ __launch_bounds__(1024) void k_cutcollect(const float* __restrict__ scores,
                                                     const uint32_t* __restrict__ hist,
                                                     uint32_t* __restrict__ meta,
                                                     uint64_t* __restrict__ keys) {
    __shared__ uint32_t lh[NBINS];        // 64 KB fine histogram
    __shared__ uint32_t coarse[1024];     // suffix sums at 16-bin granularity
    __shared__ uint32_t s_cut, cnt, cbase;

    const int tid = threadIdx.x;
    // vectorized 64 KB hist load
    const uint4* h4 = (const uint4*)hist;
    for (int i = tid; i < NBINS / 4; i += 1024) {
        uint4 v = h4[i];
        lh[i * 4 + 0] = v.x; lh[i * 4 + 1] = v.y;
        lh[i * 4 + 2] = v.z; lh[i * 4 + 3] = v.w;
    }
    if (tid == 0) { s_cut = 0u; cnt = 0u; }
    __syncthreads();

    // --- coarse sums (16 bins/thread) + suffix scan; lh keeps original counts ---
    {
        uint32_t s = 0;
#pragma unroll
        for (int b = 0; b < 16; ++b) s += lh[tid * 16 + b];
        coarse[tid] = s;
    }
    __syncthreads();
    for (int off = 1; off < 1024; off <<= 1) {
        uint32_t v = coarse[tid] + ((tid + off < 1024) ? coarse[tid + off] : 0u);
        __syncthreads();
        coarse[tid] = v;
        __syncthreads();
    }
    {
        uint32_t inc   = coarse[tid];
        uint32_t above = (tid < 1023) ? coarse[tid + 1] : 0u;
        if (above < K_TOP && inc >= K_TOP) {
            uint32_t c2 = above;
            for (int b = 15; b >= 0; --b) {
                c2 += lh[tid * 16 + b];
                if (c2 >= K_TOP) { s_cut = (uint32_t)(tid * 16 + b); break; }
            }
        }
    }
    __syncthreads();

    // --- collect this block's 1600 scores (400 float4); block-aggregated append ---
    const uint32_t cut = s_cut;
    const float4* s4 = (const float4*)(scores + blockIdx.x * 1600);
    uint32_t mybits[4], myi[4], mypos[4];
    int nc = 0;
    if (tid < 400) {
        float4 v = s4[tid];
        uint32_t bb[4] = { __float_as_uint(v.x), __float_as_uint(v.y),
                           __float_as_uint(v.z), __float_as_uint(v.w) };
        uint32_t ibase = (uint32_t)(blockIdx.x * 1600 + tid * 4);
#pragma unroll
        for (int c = 0; c < 4; ++c) {
            if ((bb[c] >> 16) >= cut) {
                mypos[nc] = atomicAdd(&cnt, 1u);
                mybits[nc] = bb[c];
                myi[nc] = ibase + (uint32_t)c;
                ++nc;
            }
        }
    }
    __syncthreads();
    if (tid == 0) cbase = cnt ? atomicAdd(&meta[2], cnt) : 0u;
    __syncthreads();
    for (int c = 0; c < nc; ++c) {
        uint32_t p = cbase + mypos[c];
        if (p < 4096u)
            keys[p] = ((uint64_t)mybits[c] << 32) | (uint64_t)(0xFFFFFFFFu - myi[c]);
    }
}

// ---------------- K4: rank (wave per candidate) + decode epilogue ----------------
__global__ __launch_bounds__(1024) void k_rank(const uint64_t* __restrict__ keys,
                                               const uint32_t* __restrict__ meta,
                                               const uint32_t* __restrict__ labels,
                                               const float* __restrict__ reg,
                                               float* __restrict__ out,
                                               float* __restrict__ boxes,
                                               uint32_t* __restrict__ lab1k) {
    __shared__ uint64_t sk[4096];
    uint32_t M = meta[2];
    if (M > 4096u) M = 4096u;
    if ((uint32_t)(blockIdx.x * 16) >= M) return;
    for (uint32_t i = threadIdx.x; i < M; i += 1024) sk[i] = keys[i];
    __syncthreads();
    int lane = threadIdx.x & 63;
    int wg = blockIdx.x * 16 + (threadIdx.x >> 6);
    if ((uint32_t)wg >= M) return;
    uint64_t mykey = sk[wg];
    uint32_t rank = 0;
    for (uint32_t j = lane; j < M; j += 64) rank += (sk[j] > mykey) ? 1u : 0u;
#pragma unroll
    for (int off = 32; off; off >>= 1) rank += __shfl_xor(rank, off);
    if (lane != 0 || rank >= K_TOP) return;
    int t = (int)rank;
    uint32_t sbits = (uint32_t)(mykey >> 32);
    uint32_t idx   = 0xFFFFFFFFu - (uint32_t)(mykey & 0xFFFFFFFFull);
    float score = __uint_as_float(sbits);
    uint32_t lab = labels[idx];
    out[t]         = score;
    out[K_TOP + t] = (float)lab;
    lab1k[t]       = lab;
    float ax = (float)(idx % FMP);
    float ay = (float)(idx / FMP);
    float4 rr = ((const float4*)reg)[idx];
    float e0 = expf(fminf(rr.x, SC_CLAMP));
    float e1 = expf(fminf(rr.y, SC_CLAMP));
    float e2 = expf(fminf(rr.z, SC_CLAMP));
    float e3 = expf(fminf(rr.w, SC_CLAMP));
    float x1 = fminf(fmaxf((ax - e0) * 4.0f / IMGF, 0.0f), 1.0f);
    float y1 = fminf(fmaxf((ay - e1) * 4.0f / IMGF, 0.0f), 1.0f);
    float x2 = fminf(fmaxf((ax + e2) * 4.0f / IMGF, 0.0f), 1.0f);
    float y2 = fminf(fmaxf((ay + e3) * 4.0f / IMGF, 0.0f), 1.0f);
    out[2 * K_TOP + t * 4 + 0] = x1;
    out[2 * K_TOP + t * 4 + 1] = y1;
    out[2 * K_TOP + t * 4 + 2] = x2;
    out[2 * K_TOP + t * 4 + 3] = y2;
    boxes[t * 4 + 0] = x1;
    boxes[t * 4 + 1] = y1;
    boxes[t * 4 + 2] = x2;
    boxes[t * 4 + 3] = y2;
}

// ---------------- K5: suppress masks, one wave per row (63 x 1024) ----------------
__global__ __launch_bounds__(1024) void k_mask(const float* __restrict__ boxes,
                                               const uint32_t* __restrict__ lab1k,
                                               uint64_t* __restrict__ mask,
                                               uint64_t* __restrict__ diag) {
    int r = blockIdx.x * 16 + (threadIdx.x >> 6);
    int lane = threadIdx.x & 63;
    if (r >= K_TOP) return;
    float4 bi = ((const float4*)boxes)[r];
    uint32_t li = lab1k[r];
    float areai = (bi.z - bi.x) * (bi.w - bi.y);
    int iw = r >> 6;
    uint64_t dw = 0ull;
#pragma unroll
    for (int w = 0; w < 16; ++w) {
        int j = w * 64 + lane;
        bool sup = false;
        if (j < K_TOP && j > r) {
            float4 bj = ((const float4*)boxes)[j];
            float areaj = (bj.z - bj.x) * (bj.w - bj.y);
            float xx1 = fmaxf(bi.x, bj.x);
            float yy1 = fmaxf(bi.y, bj.y);
            float xx2 = fminf(bi.z, bj.z);
            float yy2 = fminf(bi.w, bj.w);
            float ww = fmaxf(1e-10f, xx2 - xx1);
            float hh = fmaxf(1e-10f, yy2 - yy1);
            float inter = ww * hh;
            float iouv = inter / (areai + areaj - inter + 1e-10f);
            sup = (iouv > NMS_T) && (li == lab1k[j]);
        }
        unsigned long long m = __ballot(sup);
        if (lane == 0) mask[(size_t)r * 16 + w] = (uint64_t)m;
        if (w == iw) dw = (uint64_t)m;
    }
    if (lane == 0) diag[r] = dw;
}

// ---------------- K6: greedy scan, single wave, full register budget ----------------
// launch_bounds(64,1): VGPR cap ~512 so bun[16] (32 VGPRs) can't spill
// (earlier fused versions compiled at VGPR=40 -> scratch -> 70-100us).
__global__ __launch_bounds__(64, 1) void k_scan(const uint64_t* __restrict__ mask,
                                                const uint64_t* __restrict__ diag,
                                                float* __restrict__ out) {
    int lane = threadIdx.x;
    int q = lane >> 4, wrd = lane & 15;
    uint64_t remv = 0ull;
    uint64_t dcur = diag[lane];
    for (int g = 0; g < 16; ++g) {
        uint64_t dnxt = (g < 15) ? diag[64 * (g + 1) + lane] : 0ull;
        uint64_t bun[16];
        if (g < 15) {
#pragma unroll
            for (int r4 = 0; r4 < 16; ++r4)
                bun[r4] = mask[(size_t)(64 * g + 4 * r4 + q) * 16 + wrd];
        }
        uint32_t dlo = 0, dhi = 0;
#pragma unroll
        for (int qq = 0; qq < 4; ++qq) {
            dlo |= __builtin_amdgcn_readlane((uint32_t)remv, qq * 16 + g);
            dhi |= __builtin_amdgcn_readlane((uint32_t)(remv >> 32), qq * 16 + g);
        }
        uint64_t D = ((uint64_t)dhi << 32) | dlo;
#pragma unroll
        for (int b = 0; b < 64; ++b) {
            uint32_t tlo = __builtin_amdgcn_readlane((uint32_t)dcur, b);
            uint32_t thi = __builtin_amdgcn_readlane((uint32_t)(dcur >> 32), b);
            uint64_t T = ((uint64_t)thi << 32) | tlo;
            uint64_t sel = ((D >> b) & 1ull) - 1ull;   // ~0 if row kept
            D |= T & sel;
        }
        uint64_t keepg = ~D;
        int j = g * 64 + lane;
        if (j < K_TOP) out[6 * K_TOP + j] = (float)((keepg >> lane) & 1ull);
        if (g < 15) {
#pragma unroll
            for (int r4 = 0; r4 < 16; ++r4) {
                uint32_t kb = (uint32_t)(keepg >> (4 * r4 + q)) & 1u;
                uint64_t mm = 0ull - (uint64_t)kb;
                remv |= bun[r4] & mm;
            }
        }
        dcur = dnxt;
    }
}

extern "C" void kernel_launch(void* const* d_in, const int* in_sizes, int n_in,
                              void* d_out, int out_size, void* d_ws, size_t ws_size,
                              hipStream_t stream) {
    const float* hmp = (const float*)d_in[0];
    const float* reg = (const float*)d_in[1];
    const float* iou = (const float*)d_in[2];
    float* out = (float*)d_out;
    char* ws = (char*)d_ws;

    float*    scores = (float*)(ws + OFF_SCORES);
    uint32_t* labels = (uint32_t*)(ws + OFF_LABELS);
    uint32_t* hist   = (uint32_t*)(ws + OFF_HIST);
    uint32_t* meta   = (uint32_t*)(ws + OFF_META);
    uint64_t* keys   = (uint64_t*)(ws + OFF_KEYS);
    float*    boxes  = (float*)(ws + OFF_BOXES);
    uint32_t* lab1k  = (uint32_t*)(ws + OFF_LAB1K);
    uint64_t* mask   = (uint64_t*)(ws + OFF_MASK);
    uint64_t* diag   = (uint64_t*)(ws + OFF_DIAG);

    k_scores<<<dim3(N_ANCH * 4 / 256), dim3(256), 0, stream>>>(hmp, iou, scores, labels, hist, meta, diag);
    k_hist<<<dim3(32), dim3(1024), 0, stream>>>(scores, hist);
    k_cutcollect<<<dim3(64), dim3(1024), 0, stream>>>(scores, hist, meta, keys);
    k_rank<<<dim3(256), dim3(1024), 0, stream>>>(keys, meta, labels, reg, out, boxes, lab1k);
    k_mask<<<dim3(63), dim3(1024), 0, stream>>>(boxes, lab1k, mask, diag);
    k_scan<<<dim3(1), dim3(64), 0, stream>>>(mask, diag, out);
}

// Round 10
// 134.116 us; speedup vs baseline: 1.1760x; 1.0088x over previous
//
#include <hip/hip_runtime.h>
#include <stdint.h>

#define N_ANCH 102400
#define FMP 320
#define K_TOP 1000
#define NMS_T 0.6f
#define SC_CLAMP 6.907755278982137f
#define IMGF 1280.0f
#define NBINS 16384   // scores in (0,1) => float bits>>16 < 0x4000

// ---- workspace layout (bytes) ----
#define OFF_SCORES   0u          // f32[102400]
#define OFF_LABELS   409600u     // u32[102400]
#define OFF_HIST     819200u     // u32[16384]
#define OFF_META     884736u     // u32[64]: [2]=cand ctr
#define OFF_KEYS     884992u     // u64[4096]
#define OFF_BOXES    917760u     // f32[4000]
#define OFF_LAB1K    933760u     // u32[1000]
#define OFF_MASK     937760u     // u64[16000]
#define OFF_DIAG     1065760u    // u64[1024]

__device__ __forceinline__ float sigf(float x) {
    return 1.0f / (1.0f + expf(-x));
}

// ---------------- K1: scores+argmax; fused zeroing of hist/meta/diag ----------------
__global__ __launch_bounds__(256) void k_scores(const float* __restrict__ hmp,
                                                const float* __restrict__ iou,
                                                float* __restrict__ scores,
                                                uint32_t* __restrict__ labels,
                                                uint32_t* __restrict__ hist,
                                                uint32_t* __restrict__ meta,
                                                uint64_t* __restrict__ diag) {
    int blk = blockIdx.x;
    if (blk < 64) {
        hist[blk * 256 + threadIdx.x] = 0u;     // 64*256 = 16384 bins zeroed
    } else if (blk == 64) {
        if (threadIdx.x < 64) meta[threadIdx.x] = 0u;
        // zero diag (k_mask only rewrites rows < 1000; k_scan reads all 1024;
        // harness re-poisons ws every iteration so this is mandatory)
#pragma unroll
        for (int k = 0; k < 4; ++k) diag[threadIdx.x * 4 + k] = 0ull;
    }
    int gid = blk * 256 + threadIdx.x;
    int a = gid >> 2;
    int q = gid & 3;
    float si = sigf(iou[a]);
    const float4* row4 = (const float4*)hmp + (size_t)a * 20 + q;
    float4 v[5];
#pragma unroll
    for (int j = 0; j < 5; ++j) v[j] = row4[j * 4];
    float best = -1.0f;
    int bc = 0;
#pragma unroll
    for (int j = 0; j < 5; ++j) {
        int cb = j * 16 + q * 4;
        float f;
        f = sqrtf(sigf(v[j].x) * si); if (f > best) { best = f; bc = cb; }
        f = sqrtf(sigf(v[j].y) * si); if (f > best) { best = f; bc = cb + 1; }
        f = sqrtf(sigf(v[j].z) * si); if (f > best) { best = f; bc = cb + 2; }
        f = sqrtf(sigf(v[j].w) * si); if (f > best) { best = f; bc = cb + 3; }
    }
#pragma unroll
    for (int off = 1; off <= 2; off <<= 1) {
        float of = __shfl_xor(best, off);
        int   oc = __shfl_xor(bc, off);
        if (of > best || (of == best && oc < bc)) { best = of; bc = oc; }
    }
    if (q == 0) {
        scores[a] = best;
        labels[a] = (uint32_t)bc;
    }
}

// ---------------- K2: parallel histogram build (32 blocks), atomic flush only ----------------
// Kernel boundary is the sync. LDS pre-aggregation keeps global atomics to non-zero
// bins only (direct per-score global atomics would serialize ~100K ops on hot lines).
__global__ __launch_bounds__(1024) void k_hist(const float* __restrict__ scores,
                                               uint32_t* __restrict__ hist) {
    __shared__ uint32_t lh[NBINS];
    const int tid = threadIdx.x;
    for (int i = tid; i < NBINS; i += 1024) lh[i] = 0u;
    __syncthreads();
    // 3200 scores/block = 800 float4
    const float4* s4 = (const float4*)(scores + blockIdx.x * 3200);
    for (int k = tid; k < 800; k += 1024) {
        float4 v = s4[k];
        atomicAdd(&lh[__float_as_uint(v.x) >> 16], 1u);
        atomicAdd(&lh[__float_as_uint(v.y) >> 16], 1u);
        atomicAdd(&lh[__float_as_uint(v.z) >> 16], 1u);
        atomicAdd(&lh[__float_as_uint(v.w) >> 16], 1u);
    }
    __syncthreads();
    for (int i = tid; i < NBINS; i += 1024) {
        uint32_t c = lh[i];
        if (c) atomicAdd(&hist[i], c);
    }
}

// ---------------- K3: 64 blocks; hierarchical cut search + block-local collect ----------------
// cut = max bin b with suffix(b) >= K_TOP, a deterministic function of the complete
// hist, so all blocks agree without exchange. The old 20-barrier Hillis-Steele scan
// is replaced by: per-thread 16-bin register sums (hist straight from L2, no LDS
// staging) -> wave shfl totals -> 16-entry wave-suffix (computed redundantly by all)
// -> crossing wave does a 6-step shfl_down suffix scan -> crossing thread scans its
// 16 register bins. 2 barriers total, 76 B LDS.
__global__ __launch_bounds__(1024) void k_cutcollect(const float* __restrict__ scores,
                                                     const uint32_t* __restrict__ hist,
                                                     uint32_t* __restrict__ meta,
                                                     uint64_t* __restrict__ keys) {
    __shared__ uint32_t wsum[16];
    __shared__ uint32_t s_cut, cnt, cbase;

    const int tid = threadIdx.x;
    const int lane = tid & 63;
    const int wv = tid >> 6;

    // each thread owns 16 bins [tid*16, tid*16+16), kept in registers
    const uint4* h4 = (const uint4*)hist;
    uint4 b0 = h4[tid * 4 + 0];
    uint4 b1 = h4[tid * 4 + 1];
    uint4 b2 = h4[tid * 4 + 2];
    uint4 b3 = h4[tid * 4 + 3];
    uint32_t s = b0.x + b0.y + b0.z + b0.w + b1.x + b1.y + b1.z + b1.w
               + b2.x + b2.y + b2.z + b2.w + b3.x + b3.y + b3.z + b3.w;

    // wave totals
    uint32_t ws = s;
#pragma unroll
    for (int off = 32; off; off >>= 1) ws += __shfl_xor(ws, off);
    if (tid == 0) { s_cut = 0u; cnt = 0u; }
    if (lane == 0) wsum[wv] = ws;
    __syncthreads();

    // every thread redundantly finds the crossing wave from wsum (broadcast reads)
    {
        int wstar = 0;
        uint32_t above_w = 0;
        uint32_t acc = 0;
        for (int w = 15; w >= 0; --w) {
            uint32_t prev = acc;
            acc += wsum[w];
            if (acc >= K_TOP) { wstar = w; above_w = prev; break; }
        }
        if (wv == wstar) {
            // wave-local inclusive suffix scan of s (sum over lanes >= me)
            uint32_t suf = s;
#pragma unroll
            for (int off = 1; off < 64; off <<= 1) {
                uint32_t v = __shfl_down(suf, off);
                if (lane + off < 64) suf += v;
            }
            uint32_t sufK    = suf + above_w;   // suffix including my 16 bins
            uint32_t above_t = sufK - s;        // suffix excluding my bins
            if (above_t < K_TOP && sufK >= K_TOP) {
                uint32_t bins[16] = { b0.x, b0.y, b0.z, b0.w, b1.x, b1.y, b1.z, b1.w,
                                      b2.x, b2.y, b2.z, b2.w, b3.x, b3.y, b3.z, b3.w };
                uint32_t c2 = above_t;
                for (int b = 15; b >= 0; --b) {
                    c2 += bins[b];
                    if (c2 >= K_TOP) { s_cut = (uint32_t)(tid * 16 + b); break; }
                }
            }
        }
    }
    __syncthreads();

    // --- collect this block's 1600 scores (400 float4); block-aggregated append ---
    const uint32_t cut = s_cut;
    const float4* s4 = (const float4*)(scores + blockIdx.x * 1600);
    uint32_t mybits[4], myi[4], mypos[4];
    int nc = 0;
    if (tid < 400) {
        float4 v = s4[tid];
        uint32_t bb[4] = { __float_as_uint(v.x), __float_as_uint(v.y),
                           __float_as_uint(v.z), __float_as_uint(v.w) };
        uint32_t ibase = (uint32_t)(blockIdx.x * 1600 + tid * 4);
#pragma unroll
        for (int c = 0; c < 4; ++c) {
            if ((bb[c] >> 16) >= cut) {
                mypos[nc] = atomicAdd(&cnt, 1u);
                mybits[nc] = bb[c];
                myi[nc] = ibase + (uint32_t)c;
                ++nc;
            }
        }
    }
    __syncthreads();
    if (tid == 0) cbase = cnt ? atomicAdd(&meta[2], cnt) : 0u;
    __syncthreads();
    for (int c = 0; c < nc; ++c) {
        uint32_t p = cbase + mypos[c];
        if (p < 4096u)
            keys[p] = ((uint64_t)mybits[c] << 32) | (uint64_t)(0xFFFFFFFFu - myi[c]);
    }
}

// ---------------- K4: rank (wave per candidate) + decode epilogue ----------------
__global__ __launch_bounds__(1024) void k_rank(const uint64_t* __restrict__ keys,
                                               const uint32_t* __restrict__ meta,
                                               const uint32_t* __restrict__ labels,
                                               const float* __restrict__ reg,
                                               float* __restrict__ out,
                                               float* __restrict__ boxes,
                                               uint32_t* __restrict__ lab1k) {
    __shared__ uint64_t sk[4096];
    uint32_t M = meta[2];
    if (M > 4096u) M = 4096u;
    if ((uint32_t)(blockIdx.x * 16) >= M) return;
    for (uint32_t i = threadIdx.x; i < M; i += 1024) sk[i] = keys[i];
    __syncthreads();
    int lane = threadIdx.x & 63;
    int wg = blockIdx.x * 16 + (threadIdx.x >> 6);
    if ((uint32_t)wg >= M) return;
    uint64_t mykey = sk[wg];
    uint32_t rank = 0;
    for (uint32_t j = lane; j < M; j += 64) rank += (sk[j] > mykey) ? 1u : 0u;
#pragma unroll
    for (int off = 32; off; off >>= 1) rank += __shfl_xor(rank, off);
    if (lane != 0 || rank >= K_TOP) return;
    int t = (int)rank;
    uint32_t sbits = (uint32_t)(mykey >> 32);
    uint32_t idx   = 0xFFFFFFFFu - (uint32_t)(mykey & 0xFFFFFFFFull);
    float score = __uint_as_float(sbits);
    uint32_t lab = labels[idx];
    out[t]         = score;
    out[K_TOP + t] = (float)lab;
    lab1k[t]       = lab;
    float ax = (float)(idx % FMP);
    float ay = (float)(idx / FMP);
    float4 rr = ((const float4*)reg)[idx];
    float e0 = expf(fminf(rr.x, SC_CLAMP));
    float e1 = expf(fminf(rr.y, SC_CLAMP));
    float e2 = expf(fminf(rr.z, SC_CLAMP));
    float e3 = expf(fminf(rr.w, SC_CLAMP));
    float x1 = fminf(fmaxf((ax - e0) * 4.0f / IMGF, 0.0f), 1.0f);
    float y1 = fminf(fmaxf((ay - e1) * 4.0f / IMGF, 0.0f), 1.0f);
    float x2 = fminf(fmaxf((ax + e2) * 4.0f / IMGF, 0.0f), 1.0f);
    float y2 = fminf(fmaxf((ay + e3) * 4.0f / IMGF, 0.0f), 1.0f);
    out[2 * K_TOP + t * 4 + 0] = x1;
    out[2 * K_TOP + t * 4 + 1] = y1;
    out[2 * K_TOP + t * 4 + 2] = x2;
    out[2 * K_TOP + t * 4 + 3] = y2;
    boxes[t * 4 + 0] = x1;
    boxes[t * 4 + 1] = y1;
    boxes[t * 4 + 2] = x2;
    boxes[t * 4 + 3] = y2;
}

// ---------------- K5: suppress masks, one wave per row (63 x 1024) ----------------
__global__ __launch_bounds__(1024) void k_mask(const float* __restrict__ boxes,
                                               const uint32_t* __restrict__ lab1k,
                                               uint64_t* __restrict__ mask,
                                               uint64_t* __restrict__ diag) {
    int r = blockIdx.x * 16 + (threadIdx.x >> 6);
    int lane = threadIdx.x & 63;
    if (r >= K_TOP) return;
    float4 bi = ((const float4*)boxes)[r];
    uint32_t li = lab1k[r];
    float areai = (bi.z - bi.x) * (bi.w - bi.y);
    int iw = r >> 6;
    uint64_t dw = 0ull;
#pragma unroll
    for (int w = 0; w < 16; ++w) {
        int j = w * 64 + lane;
        bool sup = false;
        if (j < K_TOP && j > r) {
            float4 bj = ((const float4*)boxes)[j];
            float areaj = (bj.z - bj.x) * (bj.w - bj.y);
            float xx1 = fmaxf(bi.x, bj.x);
            float yy1 = fmaxf(bi.y, bj.y);
            float xx2 = fminf(bi.z, bj.z);
            float yy2 = fminf(bi.w, bj.w);
            float ww = fmaxf(1e-10f, xx2 - xx1);
            float hh = fmaxf(1e-10f, yy2 - yy1);
            float inter = ww * hh;
            float iouv = inter / (areai + areaj - inter + 1e-10f);
            sup = (iouv > NMS_T) && (li == lab1k[j]);
        }
        unsigned long long m = __ballot(sup);
        if (lane == 0) mask[(size_t)r * 16 + w] = (uint64_t)m;
        if (w == iw) dw = (uint64_t)m;
    }
    if (lane == 0) diag[r] = dw;
}

// ---------------- K6: greedy scan, single wave, full register budget ----------------
// launch_bounds(64,1): VGPR cap ~512 so bun[16] (32 VGPRs) can't spill
// (earlier fused versions compiled at VGPR=40 -> scratch -> 70-100us).
__global__ __launch_bounds__(64, 1) void k_scan(const uint64_t* __restrict__ mask,
                                                const uint64_t* __restrict__ diag,
                                                float* __restrict__ out) {
    int lane = threadIdx.x;
    int q = lane >> 4, wrd = lane & 15;
    uint64_t remv = 0ull;
    uint64_t dcur = diag[lane];
    for (int g = 0; g < 16; ++g) {
        uint64_t dnxt = (g < 15) ? diag[64 * (g + 1) + lane] : 0ull;
        uint64_t bun[16];
        if (g < 15) {
#pragma unroll
            for (int r4 = 0; r4 < 16; ++r4)
                bun[r4] = mask[(size_t)(64 * g + 4 * r4 + q) * 16 + wrd];
        }
        uint32_t dlo = 0, dhi = 0;
#pragma unroll
        for (int qq = 0; qq < 4; ++qq) {
            dlo |= __builtin_amdgcn_readlane((uint32_t)remv, qq * 16 + g);
            dhi |= __builtin_amdgcn_readlane((uint32_t)(remv >> 32), qq * 16 + g);
        }
        uint64_t D = ((uint64_t)dhi << 32) | dlo;
#pragma unroll
        for (int b = 0; b < 64; ++b) {
            uint32_t tlo = __builtin_amdgcn_readlane((uint32_t)dcur, b);
            uint32_t thi = __builtin_amdgcn_readlane((uint32_t)(dcur >> 32), b);
            uint64_t T = ((uint64_t)thi << 32) | tlo;
            uint64_t sel = ((D >> b) & 1ull) - 1ull;   // ~0 if row kept
            D |= T & sel;
        }
        uint64_t keepg = ~D;
        int j = g * 64 + lane;
        if (j < K_TOP) out[6 * K_TOP + j] = (float)((keepg >> lane) & 1ull);
        if (g < 15) {
#pragma unroll
            for (int r4 = 0; r4 < 16; ++r4) {
                uint32_t kb = (uint32_t)(keepg >> (4 * r4 + q)) & 1u;
                uint64_t mm = 0ull - (uint64_t)kb;
                remv |= bun[r4] & mm;
            }
        }
        dcur = dnxt;
    }
}

extern "C" void kernel_launch(void* const* d_in, const int* in_sizes, int n_in,
                              void* d_out, int out_size, void* d_ws, size_t ws_size,
                              hipStream_t stream) {
    const float* hmp = (const float*)d_in[0];
    const float* reg = (const float*)d_in[1];
    const float* iou = (const float*)d_in[2];
    float* out = (float*)d_out;
    char* ws = (char*)d_ws;

    float*    scores = (float*)(ws + OFF_SCORES);
    uint32_t* labels = (uint32_t*)(ws + OFF_LABELS);
    uint32_t* hist   = (uint32_t*)(ws + OFF_HIST);
    uint32_t* meta   = (uint32_t*)(ws + OFF_META);
    uint64_t* keys   = (uint64_t*)(ws + OFF_KEYS);
    float*    boxes  = (float*)(ws + OFF_BOXES);
    uint32_t* lab1k  = (uint32_t*)(ws + OFF_LAB1K);
    uint64_t* mask   = (uint64_t*)(ws + OFF_MASK);
    uint64_t* diag   = (uint64_t*)(ws + OFF_DIAG);

    k_scores<<<dim3(N_ANCH * 4 / 256), dim3(256), 0, stream>>>(hmp, iou, scores, labels, hist, meta, diag);
    k_hist<<<dim3(32), dim3(1024), 0, stream>>>(scores, hist);
    k_cutcollect<<<dim3(64), dim3(1024), 0, stream>>>(scores, hist, meta, keys);
    k_rank<<<dim3(256), dim3(1024), 0, stream>>>(keys, meta, labels, reg, out, boxes, lab1k);
    k_mask<<<dim3(63), dim3(1024), 0, stream>>>(boxes, lab1k, mask, diag);
    k_scan<<<dim3(1), dim3(64), 0, stream>>>(mask, diag, out);
}